// Round 2
// baseline (3311.518 us; speedup 1.0000x reference)
//
#include <hip/hip_runtime.h>
#include <math.h>

// Problem constants (match reference)
#define BB 256
#define TT 512
#define SS 64
#define OO 128
#define HH 128
#define FH 512  // 4*H
#define CH 16   // time-chunk for fused obs@K staging

#define LOG2PI_F 1.8378770664093453f

// ws layout (bytes): [acc: 8B][pad][qpm: B*T*S*4 = 32MB]  -> total ~32MB
#define ACC_OFF 0
#define QPM_OFF 256

__device__ __forceinline__ float softplusf(float x) {
    // matches jax.nn.softplus: max(x,0) + log1p(exp(-|x|))
    return fmaxf(x, 0.f) + log1pf(expf(-fabsf(x)));
}
__device__ __forceinline__ float sigmoidf(float x) {
    return 1.f / (1.f + expf(-x));
}

__global__ void zero_acc_kernel(double* acc) { acc[0] = 0.0; }
__global__ void finalize_kernel(const double* acc, float* out) { out[0] = (float)acc[0]; }

// ---------------------------------------------------------------------------
// Fused kernel: per batch b (256 blocks x 512 threads = 8 waves):
//   - chunked obs@K (staged obs in LDS, K from global/L2, az[] in registers)
//   - sequential LSTM over T (thread t owns R_lstm column t in 128 VGPRs)
//   - prior rollout m@Wf (threads 256..511, half-column each)
//   - posterior heads h@Wr (threads 0..255, half-column each) + KL accum
// Writes: qpm [B,T,S] (post_mean, needed by generator kernel) + KL atomic.
// ---------------------------------------------------------------------------
__global__ __launch_bounds__(512, 2) void kFused(
    const float* __restrict__ obs, const float* __restrict__ K,
    const float* __restrict__ bl,  const float* __restrict__ Rw,
    const float* __restrict__ Wfm, const float* __restrict__ bfm,
    const float* __restrict__ Wfs, const float* __restrict__ bfs,
    const float* __restrict__ im,
    const float* __restrict__ Wrm, const float* __restrict__ brm,
    const float* __restrict__ Wrs, const float* __restrict__ brs,
    float* __restrict__ qpm, double* __restrict__ acc_out)
{
    __shared__ float sobsT[128 * CH];   // obs chunk transposed: [k][s]
    __shared__ float h_lds[128];
    __shared__ float m_lds[64];
    __shared__ float zbuf[512];
    __shared__ float Pf[2 * 132];       // prior partials (2-way k-split)
    __shared__ float Pr[2 * 132];       // Wr-head partials (2-way k-split)
    __shared__ float prm[64], prs[64], sps[64];
    __shared__ float red[64];

    const int t = threadIdx.x;
    const int b = blockIdx.x;

    // R_lstm column t
    float rc[128];
#pragma unroll
    for (int k = 0; k < 128; ++k) rc[k] = Rw[k * 512 + t];
    const float zb = bl[t];

    // aux: t<256 -> Wr half-column (64 regs); t>=256 -> Wf half-column (32 regs)
    float aux[64];
    const int colw = t & 127;
    const int kh = (t >> 7) & 1;
    if (t < 256) {
        const float* W = (colw < 64) ? Wrm : Wrs;
        const int c = colw & 63;
#pragma unroll
        for (int kk = 0; kk < 64; ++kk) aux[kk] = W[(kh * 64 + kk) * 64 + c];
    } else {
        const float* W = (colw < 64) ? Wfm : Wfs;
        const int c = colw & 63;
#pragma unroll
        for (int kk = 0; kk < 32; ++kk) aux[kk] = W[(kh * 32 + kk) * 64 + c];
    }
    float bfv = 0.f, brv = 0.f;
    if (t < 128) {
        bfv = (t < 64) ? bfm[t] : bfs[t - 64];
        brv = (t < 64) ? brm[t] : brs[t - 64];
    }

    float cst = 0.f;    // LSTM cell state (t<128)
    float acckl = 0.f;  // KL accumulator (t<64)
    if (t < 128) h_lds[t] = 0.f;
    if (t < 64)  m_lds[t] = im[b * 64 + t];
    __syncthreads();

    const float* obsb = obs + (size_t)b * TT * OO;
    float* qrow = qpm + (size_t)b * TT * SS;

    for (int t0 = 0; t0 < TT; t0 += CH) {
        // ---- stage obs chunk transposed: sobsT[k*CH+s] = obs[b, t0+s, k] ----
        {
            const float4 v = ((const float4*)(obsb + (size_t)t0 * OO))[t];
            const int s  = (4 * t) >> 7;   // 0..15
            const int k0 = (4 * t) & 127;
            sobsT[(k0 + 0) * CH + s] = v.x;
            sobsT[(k0 + 1) * CH + s] = v.y;
            sobsT[(k0 + 2) * CH + s] = v.z;
            sobsT[(k0 + 3) * CH + s] = v.w;
        }
        __syncthreads();

        // ---- az[s] = obs_chunk @ K[:, t]  (K from global, L2-resident) ----
        float az[CH];
#pragma unroll
        for (int s = 0; s < CH; ++s) az[s] = 0.f;
#pragma unroll 4
        for (int k = 0; k < 128; ++k) {
            const float kv = K[k * 512 + t];
            const float4* o4 = (const float4*)&sobsT[k * CH];
#pragma unroll
            for (int s4 = 0; s4 < CH / 4; ++s4) {
                const float4 o = o4[s4];
                az[s4 * 4 + 0] += o.x * kv;
                az[s4 * 4 + 1] += o.y * kv;
                az[s4 * 4 + 2] += o.z * kv;
                az[s4 * 4 + 3] += o.w * kv;
            }
        }

        // ---- sequential steps within the chunk ----
#pragma unroll
        for (int si = 0; si < CH; ++si) {
            const int ts = t0 + si;

            // phase 1: z[t] = az + bias + h @ R[:,t]; prior partials (t>=256)
            {
                const float4* h4 = (const float4*)h_lds;
                float a0 = 0.f, a1 = 0.f, a2 = 0.f, a3 = 0.f;
#pragma unroll
                for (int kb = 0; kb < 32; ++kb) {
                    const float4 v = h4[kb];
                    a0 += v.x * rc[kb * 4 + 0];
                    a1 += v.y * rc[kb * 4 + 1];
                    a2 += v.z * rc[kb * 4 + 2];
                    a3 += v.w * rc[kb * 4 + 3];
                }
                zbuf[t] = az[si] + zb + ((a0 + a1) + (a2 + a3));
            }
            if (t >= 256) {
                const float4* m4 = (const float4*)&m_lds[kh * 32];
                float p0 = 0.f, p1 = 0.f, p2 = 0.f, p3 = 0.f;
#pragma unroll
                for (int kb = 0; kb < 8; ++kb) {
                    const float4 v = m4[kb];
                    p0 += v.x * aux[kb * 4 + 0];
                    p1 += v.y * aux[kb * 4 + 1];
                    p2 += v.z * aux[kb * 4 + 2];
                    p3 += v.w * aux[kb * 4 + 3];
                }
                Pf[kh * 132 + colw] = (p0 + p1) + (p2 + p3);
            }
            __syncthreads();  // B1: zbuf, Pf ready

            // phase 2: gates + cell update; prior finish
            if (t < 128) {
                const float zi = zbuf[t];
                const float zf = zbuf[t + 128];
                const float zg = zbuf[t + 256];
                const float zo = zbuf[t + 384];
                cst = sigmoidf(zf) * cst + sigmoidf(zi) * tanhf(zg);
                const float h = sigmoidf(zo) * tanhf(cst);
                h_lds[t] = h;
                const float pacc = Pf[t] + Pf[132 + t] + bfv;
                if (t < 64) { m_lds[t] = pacc; prm[t] = pacc; }
                else        { prs[t - 64] = softplusf(pacc); }
            }
            __syncthreads();  // B2: h_lds, m_lds, prm/prs ready

            // phase 3: Wr-head partials (t<256)
            if (t < 256) {
                const float4* h4 = (const float4*)&h_lds[kh * 64];
                float a0 = 0.f, a1 = 0.f, a2 = 0.f, a3 = 0.f;
#pragma unroll
                for (int kb = 0; kb < 16; ++kb) {
                    const float4 v = h4[kb];
                    a0 += v.x * aux[kb * 4 + 0];
                    a1 += v.y * aux[kb * 4 + 1];
                    a2 += v.z * aux[kb * 4 + 2];
                    a3 += v.w * aux[kb * 4 + 3];
                }
                Pr[kh * 132 + colw] = (a0 + a1) + (a2 + a3);
            }
            __syncthreads();  // B3: Pr ready

            // phase 4: finish heads
            float pmv = 0.f;
            if (t < 128) {
                const float wz = Pr[t] + Pr[132 + t] + brv;
                if (t < 64) { pmv = wz; qrow[(size_t)ts * SS + t] = wz; }
                else        { sps[t - 64] = softplusf(wz); }
            }
            __syncthreads();  // B4: sps ready

            // phase 5: KL accumulate (t<64)
            if (t < 64) {
                const float sp = sps[t];
                const float sq = prs[t];
                const float d  = pmv - prm[t];
                acckl += logf(sq) - logf(sp)
                       + (sp * sp + d * d) / (2.f * sq * sq) - 0.5f;
            }
        }
    }

    // block-reduce KL (t<64) -> atomic
    if (t < 64) red[t] = acckl;
    __syncthreads();
    if (t < 32) red[t] += red[t + 32];
    __syncthreads();
    if (t < 16) red[t] += red[t + 16];
    __syncthreads();
    if (t < 8) red[t] += red[t + 8];
    __syncthreads();
    if (t < 4) red[t] += red[t + 4];
    __syncthreads();
    if (t < 2) red[t] += red[t + 2];
    __syncthreads();
    if (t == 0) {
        const float kl = red[0] + red[1];
        atomicAdd(acc_out, (double)kl * (1.0 / ((double)BB * (double)TT)));
    }
}

// ---------------- Kernel C2: generator heads + reconstruction -----------------
// 128 threads: thread t owns Wg_m[:,t] and Wg_s[:,t] (64+64 regs). 128 pos/block.
__global__ __launch_bounds__(128) void kC2(const float* __restrict__ obs,
                                           const float* __restrict__ qpm,
                                           const float* __restrict__ Wgm,
                                           const float* __restrict__ bgm,
                                           const float* __restrict__ Wgs,
                                           const float* __restrict__ bgs,
                                           double* __restrict__ acc_out) {
    __shared__ float red[128];
    const int t = threadIdx.x;
    float wgm[64], wgs[64];
#pragma unroll
    for (int k = 0; k < 64; ++k) {
        wgm[k] = Wgm[k * 128 + t];
        wgs[k] = Wgs[k * 128 + t];
    }
    const float bm = bgm[t];
    const float bs = bgs[t];

    float accr = 0.f;
    const size_t p0 = (size_t)blockIdx.x * 128;
    for (int i = 0; i < 128; ++i) {
        const size_t p = p0 + i;
        const float4* m4 = (const float4*)(qpm + p * 64);
        float m0 = 0.f, m1 = 0.f, m2 = 0.f, m3 = 0.f;
        float s0 = 0.f, s1 = 0.f, s2 = 0.f, s3 = 0.f;
#pragma unroll
        for (int kb = 0; kb < 16; ++kb) {
            const float4 v = m4[kb];
            m0 += v.x * wgm[kb * 4 + 0];
            m1 += v.y * wgm[kb * 4 + 1];
            m2 += v.z * wgm[kb * 4 + 2];
            m3 += v.w * wgm[kb * 4 + 3];
            s0 += v.x * wgs[kb * 4 + 0];
            s1 += v.y * wgs[kb * 4 + 1];
            s2 += v.z * wgs[kb * 4 + 2];
            s3 += v.w * wgs[kb * 4 + 3];
        }
        const float om = bm + ((m0 + m1) + (m2 + m3));
        const float os = softplusf(bs + ((s0 + s1) + (s2 + s3)));
        const float x = obs[p * 128 + t];
        const float d = (x - om) / os;
        accr += 0.5f * d * d + logf(os) + 0.5f * LOG2PI_F;
    }
    red[t] = accr;
    __syncthreads();
    for (int s = 64; s > 0; s >>= 1) {
        if (t < s) red[t] += red[t + s];
        __syncthreads();
    }
    if (t == 0) atomicAdd(acc_out, (double)red[0] * (1.0 / (double)BB));
}

extern "C" void kernel_launch(void* const* d_in, const int* in_sizes, int n_in,
                              void* d_out, int out_size, void* d_ws, size_t ws_size,
                              hipStream_t stream) {
    (void)in_sizes; (void)n_in; (void)out_size; (void)ws_size;

    const float* obs = (const float*)d_in[0];
    const float* im  = (const float*)d_in[1];
    // d_in[2] initial_scale: unused by the reference forward
    const float* Wfm = (const float*)d_in[3];
    const float* bfm = (const float*)d_in[4];
    const float* Wfs = (const float*)d_in[5];
    const float* bfs = (const float*)d_in[6];
    const float* Wgm = (const float*)d_in[7];
    const float* bgm = (const float*)d_in[8];
    const float* Wgs = (const float*)d_in[9];
    const float* bgs = (const float*)d_in[10];
    const float* K   = (const float*)d_in[11];
    const float* Rw  = (const float*)d_in[12];
    const float* bl  = (const float*)d_in[13];
    const float* Wrm = (const float*)d_in[14];
    const float* brm = (const float*)d_in[15];
    const float* Wrs = (const float*)d_in[16];
    const float* brs = (const float*)d_in[17];

    double* acc = (double*)((char*)d_ws + ACC_OFF);
    float* qpm  = (float*)((char*)d_ws + QPM_OFF);

    zero_acc_kernel<<<1, 1, 0, stream>>>(acc);
    kFused<<<BB, 512, 0, stream>>>(obs, K, bl, Rw, Wfm, bfm, Wfs, bfs, im,
                                   Wrm, brm, Wrs, brs, qpm, acc);
    kC2<<<(BB * TT) / 128, 128, 0, stream>>>(obs, qpm, Wgm, bgm, Wgs, bgs, acc);
    finalize_kernel<<<1, 1, 0, stream>>>(acc, (float*)d_out);
}

// Round 3
// 2039.165 us; speedup vs baseline: 1.6240x; 1.6240x over previous
//
#include <hip/hip_runtime.h>
#include <math.h>

// Problem constants (match reference)
#define BB 256
#define TT 512
#define SS 64
#define OO 128
#define HH 128
#define FH 512  // 4*H
#define CH 16   // time-chunk for fused obs@K staging

#define LOG2PI_F 1.8378770664093453f

// ws layout (bytes): [acc: 8B][pad][qpm: B*T*S*4 = 32MB]
#define ACC_OFF 0
#define QPM_OFF 256

__device__ __forceinline__ float softplusf(float x) {
    // matches jax.nn.softplus: max(x,0) + log1p(exp(-|x|))
    return fmaxf(x, 0.f) + log1pf(expf(-fabsf(x)));
}
__device__ __forceinline__ float sigmoidf(float x) {
    return 1.f / (1.f + expf(-x));
}

__global__ void zero_acc_kernel(double* acc) { acc[0] = 0.0; }
__global__ void finalize_kernel(const double* acc, float* out) { out[0] = (float)acc[0]; }

// ---------------------------------------------------------------------------
// Fused kernel: one block per batch (256 blocks x 512 threads = 8 waves).
//  - chunked obs@K: obs chunk staged transposed in LDS, K from global (L2-hot),
//    az[CH] per-thread in registers
//  - sequential LSTM: thread t owns R_lstm column t (128 VGPRs)
//  - prior rollout m@Wf: 4-way k-split across all threads (wf[16])
//  - posterior head h@Wr: 4-way k-split across all threads (wr[32]),
//    pipelined one step behind the recurrence -> 2 barriers per step
// phase2 roles: waves0-1 gates | wave6 prior finish | wave2 head finish + KL
// ---------------------------------------------------------------------------
__global__ __launch_bounds__(512, 1) void kFused(
    const float* __restrict__ obs, const float* __restrict__ K,
    const float* __restrict__ bl,  const float* __restrict__ Rw,
    const float* __restrict__ Wfm, const float* __restrict__ bfm,
    const float* __restrict__ Wfs, const float* __restrict__ bfs,
    const float* __restrict__ im,
    const float* __restrict__ Wrm, const float* __restrict__ brm,
    const float* __restrict__ Wrs, const float* __restrict__ brs,
    float* __restrict__ qpm, double* __restrict__ acc_out)
{
    __shared__ float sobsT[128 * CH];   // obs chunk transposed: [k][s]
    __shared__ float h_lds[128];
    __shared__ float m_lds[64];
    __shared__ float zbuf[512];
    __shared__ float Pf[4 * 132];       // prior partials (4-way k-split)
    __shared__ float Pr[4 * 132];       // head partials  (4-way k-split)
    __shared__ float prm2[2][64];       // prior mean, double-buffered by ts&1
    __shared__ float prs2[2][64];       // prior scale, double-buffered

    const int t = threadIdx.x;
    const int b = blockIdx.x;

    // R_lstm column t
    float rc[128];
#pragma unroll
    for (int k = 0; k < 128; ++k) rc[k] = Rw[k * 512 + t];
    const float zb = bl[t];

    // 4-way k-split columns for Wr (K=128 -> 32 rows) and Wf (K=64 -> 16 rows)
    const int colw = t & 127;   // 0..63 mean cols, 64..127 scale cols
    const int kq = t >> 7;      // k-quarter 0..3
    float wr[32], wf[16];
    {
        const int c = colw & 63;
        const float* Wr_ = (colw < 64) ? Wrm : Wrs;
#pragma unroll
        for (int kk = 0; kk < 32; ++kk) wr[kk] = Wr_[(kq * 32 + kk) * 64 + c];
        const float* Wf_ = (colw < 64) ? Wfm : Wfs;
#pragma unroll
        for (int kk = 0; kk < 16; ++kk) wf[kk] = Wf_[(kq * 16 + kk) * 64 + c];
    }
    // role biases: wave6 (prior finish) and wave2 (head finish)
    float bA = 0.f, bB = 0.f;
    if (t >= 384 && t < 448) { bA = bfm[t - 384]; bB = bfs[t - 384]; }
    if (t >= 128 && t < 192) { bA = brm[t - 128]; bB = brs[t - 128]; }

    float cst = 0.f;    // LSTM cell state (t<128)
    float acckl = 0.f;  // KL accumulator (wave2)
    if (t < 128) h_lds[t] = 0.f;
    if (t < 64)  m_lds[t] = im[b * 64 + t];
    __syncthreads();

    const float* obsb = obs + (size_t)b * TT * OO;
    float* qrow = qpm + (size_t)b * TT * SS;

    for (int t0 = 0; t0 < TT; t0 += CH) {
        // ---- stage obs chunk transposed: sobsT[k*CH+s] = obs[b, t0+s, k] ----
        {
            const float4 v = ((const float4*)(obsb + (size_t)t0 * OO))[t];
            const int s  = (4 * t) >> 7;   // 0..15
            const int k0 = (4 * t) & 127;
            sobsT[(k0 + 0) * CH + s] = v.x;
            sobsT[(k0 + 1) * CH + s] = v.y;
            sobsT[(k0 + 2) * CH + s] = v.z;
            sobsT[(k0 + 3) * CH + s] = v.w;
        }
        __syncthreads();

        // ---- az[s] = obs_chunk @ K[:, t]  (K global, L2-resident) ----
        float az[CH];
#pragma unroll
        for (int s = 0; s < CH; ++s) az[s] = 0.f;
#pragma unroll 4
        for (int k = 0; k < 128; ++k) {
            const float kv = K[k * 512 + t];
            const float4* o4 = (const float4*)&sobsT[k * CH];
#pragma unroll
            for (int s4 = 0; s4 < CH / 4; ++s4) {
                const float4 o = o4[s4];
                az[s4 * 4 + 0] += o.x * kv;
                az[s4 * 4 + 1] += o.y * kv;
                az[s4 * 4 + 2] += o.z * kv;
                az[s4 * 4 + 3] += o.w * kv;
            }
        }

        // ---- sequential steps within the chunk (2 barriers/step) ----
#pragma unroll
        for (int si = 0; si < CH; ++si) {
            const int ts = t0 + si;

            // ===== phase 1 (all threads): z matvec, Wf partials, Wr partials
            {
                const float4* h4 = (const float4*)h_lds;
                float a0 = 0.f, a1 = 0.f, a2 = 0.f, a3 = 0.f;
#pragma unroll
                for (int kb = 0; kb < 32; ++kb) {
                    const float4 v = h4[kb];
                    a0 += v.x * rc[kb * 4 + 0];
                    a1 += v.y * rc[kb * 4 + 1];
                    a2 += v.z * rc[kb * 4 + 2];
                    a3 += v.w * rc[kb * 4 + 3];
                }
                zbuf[t] = az[si] + zb + ((a0 + a1) + (a2 + a3));
            }
            {   // head partials for h_{ts-1}
                const float4* h4 = (const float4*)&h_lds[kq * 32];
                float a0 = 0.f, a1 = 0.f, a2 = 0.f, a3 = 0.f;
#pragma unroll
                for (int kb = 0; kb < 8; ++kb) {
                    const float4 v = h4[kb];
                    a0 += v.x * wr[kb * 4 + 0];
                    a1 += v.y * wr[kb * 4 + 1];
                    a2 += v.z * wr[kb * 4 + 2];
                    a3 += v.w * wr[kb * 4 + 3];
                }
                Pr[kq * 132 + colw] = (a0 + a1) + (a2 + a3);
            }
            {   // prior partials for m_ts
                const float4* m4 = (const float4*)&m_lds[kq * 16];
                float p0 = 0.f, p1 = 0.f, p2 = 0.f, p3 = 0.f;
#pragma unroll
                for (int kb = 0; kb < 4; ++kb) {
                    const float4 v = m4[kb];
                    p0 += v.x * wf[kb * 4 + 0];
                    p1 += v.y * wf[kb * 4 + 1];
                    p2 += v.z * wf[kb * 4 + 2];
                    p3 += v.w * wf[kb * 4 + 3];
                }
                Pf[kq * 132 + colw] = (p0 + p1) + (p2 + p3);
            }
            __syncthreads();  // B1

            // ===== phase 2 (role-split)
            if (t < 128) {
                // LSTM gates + cell/hidden update
                const float zi = zbuf[t];
                const float zf = zbuf[t + 128];
                const float zg = zbuf[t + 256];
                const float zo = zbuf[t + 384];
                cst = sigmoidf(zf) * cst + sigmoidf(zi) * tanhf(zg);
                h_lds[t] = sigmoidf(zo) * tanhf(cst);
            } else if (t >= 384 && t < 448) {
                // prior finish: emit (pm, ps) for ts; m <- pm
                const int c = t - 384;
                const float pm = Pf[c] + Pf[132 + c] + Pf[264 + c] + Pf[396 + c] + bA;
                const float pz = Pf[64 + c] + Pf[196 + c] + Pf[328 + c] + Pf[460 + c] + bB;
                m_lds[c] = pm;
                prm2[ts & 1][c] = pm;
                prs2[ts & 1][c] = softplusf(pz);
            } else if (t >= 128 && t < 192 && ts > 0) {
                // head finish + KL for step ts-1
                const int c = t - 128;
                const float qm = Pr[c] + Pr[132 + c] + Pr[264 + c] + Pr[396 + c] + bA;
                const float qz = Pr[64 + c] + Pr[196 + c] + Pr[328 + c] + Pr[460 + c] + bB;
                const float sp = softplusf(qz);
                qrow[(size_t)(ts - 1) * SS + c] = qm;
                const float pm = prm2[(ts - 1) & 1][c];
                const float sq = prs2[(ts - 1) & 1][c];
                const float d = qm - pm;
                acckl += logf(sq) - logf(sp) + (sp * sp + d * d) / (2.f * sq * sq) - 0.5f;
            }
            __syncthreads();  // B2
        }
    }

    // ---- drain: head + KL for ts = TT-1 (h_lds = h_{TT-1}) ----
    {
        const float4* h4 = (const float4*)&h_lds[kq * 32];
        float a0 = 0.f, a1 = 0.f, a2 = 0.f, a3 = 0.f;
#pragma unroll
        for (int kb = 0; kb < 8; ++kb) {
            const float4 v = h4[kb];
            a0 += v.x * wr[kb * 4 + 0];
            a1 += v.y * wr[kb * 4 + 1];
            a2 += v.z * wr[kb * 4 + 2];
            a3 += v.w * wr[kb * 4 + 3];
        }
        Pr[kq * 132 + colw] = (a0 + a1) + (a2 + a3);
    }
    __syncthreads();
    if (t >= 128 && t < 192) {
        const int c = t - 128;
        const int ts = TT - 1;
        const float qm = Pr[c] + Pr[132 + c] + Pr[264 + c] + Pr[396 + c] + bA;
        const float qz = Pr[64 + c] + Pr[196 + c] + Pr[328 + c] + Pr[460 + c] + bB;
        const float sp = softplusf(qz);
        qrow[(size_t)ts * SS + c] = qm;
        const float pm = prm2[ts & 1][c];
        const float sq = prs2[ts & 1][c];
        const float d = qm - pm;
        acckl += logf(sq) - logf(sp) + (sp * sp + d * d) / (2.f * sq * sq) - 0.5f;
    }
    __syncthreads();

    // ---- block-reduce KL (wave2's 64 values) -> atomic ----
    if (t >= 128 && t < 192) zbuf[t - 128] = acckl;
    __syncthreads();
    if (t < 32) zbuf[t] += zbuf[t + 32];
    __syncthreads();
    if (t < 16) zbuf[t] += zbuf[t + 16];
    __syncthreads();
    if (t < 8) zbuf[t] += zbuf[t + 8];
    __syncthreads();
    if (t < 4) zbuf[t] += zbuf[t + 4];
    __syncthreads();
    if (t < 2) zbuf[t] += zbuf[t + 2];
    __syncthreads();
    if (t == 0) {
        atomicAdd(acc_out, (double)(zbuf[0] + zbuf[1]) * (1.0 / ((double)BB * (double)TT)));
    }
}

// ---------------- Kernel C2: generator heads + reconstruction -----------------
// 128 threads: thread t owns Wg_m[:,t] and Wg_s[:,t] (64+64 regs). 128 pos/block.
__global__ __launch_bounds__(128) void kC2(const float* __restrict__ obs,
                                           const float* __restrict__ qpm,
                                           const float* __restrict__ Wgm,
                                           const float* __restrict__ bgm,
                                           const float* __restrict__ Wgs,
                                           const float* __restrict__ bgs,
                                           double* __restrict__ acc_out) {
    __shared__ float red[128];
    const int t = threadIdx.x;
    float wgm[64], wgs[64];
#pragma unroll
    for (int k = 0; k < 64; ++k) {
        wgm[k] = Wgm[k * 128 + t];
        wgs[k] = Wgs[k * 128 + t];
    }
    const float bm = bgm[t];
    const float bs = bgs[t];

    float accr = 0.f;
    const size_t p0 = (size_t)blockIdx.x * 128;
    for (int i = 0; i < 128; ++i) {
        const size_t p = p0 + i;
        const float4* m4 = (const float4*)(qpm + p * 64);
        float m0 = 0.f, m1 = 0.f, m2 = 0.f, m3 = 0.f;
        float s0 = 0.f, s1 = 0.f, s2 = 0.f, s3 = 0.f;
#pragma unroll
        for (int kb = 0; kb < 16; ++kb) {
            const float4 v = m4[kb];
            m0 += v.x * wgm[kb * 4 + 0];
            m1 += v.y * wgm[kb * 4 + 1];
            m2 += v.z * wgm[kb * 4 + 2];
            m3 += v.w * wgm[kb * 4 + 3];
            s0 += v.x * wgs[kb * 4 + 0];
            s1 += v.y * wgs[kb * 4 + 1];
            s2 += v.z * wgs[kb * 4 + 2];
            s3 += v.w * wgs[kb * 4 + 3];
        }
        const float om = bm + ((m0 + m1) + (m2 + m3));
        const float os = softplusf(bs + ((s0 + s1) + (s2 + s3)));
        const float x = obs[p * 128 + t];
        const float d = (x - om) / os;
        accr += 0.5f * d * d + logf(os) + 0.5f * LOG2PI_F;
    }
    red[t] = accr;
    __syncthreads();
    for (int s = 64; s > 0; s >>= 1) {
        if (t < s) red[t] += red[t + s];
        __syncthreads();
    }
    if (t == 0) atomicAdd(acc_out, (double)red[0] * (1.0 / (double)BB));
}

extern "C" void kernel_launch(void* const* d_in, const int* in_sizes, int n_in,
                              void* d_out, int out_size, void* d_ws, size_t ws_size,
                              hipStream_t stream) {
    (void)in_sizes; (void)n_in; (void)out_size; (void)ws_size;

    const float* obs = (const float*)d_in[0];
    const float* im  = (const float*)d_in[1];
    // d_in[2] initial_scale: unused by the reference forward
    const float* Wfm = (const float*)d_in[3];
    const float* bfm = (const float*)d_in[4];
    const float* Wfs = (const float*)d_in[5];
    const float* bfs = (const float*)d_in[6];
    const float* Wgm = (const float*)d_in[7];
    const float* bgm = (const float*)d_in[8];
    const float* Wgs = (const float*)d_in[9];
    const float* bgs = (const float*)d_in[10];
    const float* K   = (const float*)d_in[11];
    const float* Rw  = (const float*)d_in[12];
    const float* bl  = (const float*)d_in[13];
    const float* Wrm = (const float*)d_in[14];
    const float* brm = (const float*)d_in[15];
    const float* Wrs = (const float*)d_in[16];
    const float* brs = (const float*)d_in[17];

    double* acc = (double*)((char*)d_ws + ACC_OFF);
    float* qpm  = (float*)((char*)d_ws + QPM_OFF);

    zero_acc_kernel<<<1, 1, 0, stream>>>(acc);
    kFused<<<BB, 512, 0, stream>>>(obs, K, bl, Rw, Wfm, bfm, Wfs, bfs, im,
                                   Wrm, brm, Wrs, brs, qpm, acc);
    kC2<<<(BB * TT) / 128, 128, 0, stream>>>(obs, qpm, Wgm, bgm, Wgs, bgs, acc);
    finalize_kernel<<<1, 1, 0, stream>>>(acc, (float*)d_out);
}

// Round 5
// 1841.032 us; speedup vs baseline: 1.7987x; 1.1076x over previous
//
#include <hip/hip_runtime.h>
#include <math.h>

// Problem constants (match reference)
#define BB 256
#define TT 512
#define SS 64
#define OO 128
#define HH 128
#define FH 512  // 4*H
#define CH 16   // time-chunk

#define LOG2PI_F 1.8378770664093453f

// ws layout (bytes): [acc: 8B][pad][qpm: B*T*S*4 = 32MB]
#define ACC_OFF 0
#define QPM_OFF 256

__device__ __forceinline__ float softplusf(float x) {
    // matches jax.nn.softplus: max(x,0) + log1p(exp(-|x|))
    return fmaxf(x, 0.f) + log1pf(expf(-fabsf(x)));
}
__device__ __forceinline__ float sigmoidf(float x) {
    return 1.f / (1.f + expf(-x));
}

__global__ void zero_acc_kernel(double* acc) { acc[0] = 0.0; }
__global__ void finalize_kernel(const double* acc, float* out) { out[0] = (float)acc[0]; }

// ---------------------------------------------------------------------------
// Fused kernel: one block per batch (256 blocks x 1024 threads = 16 waves).
// Register budget target <=128 VGPR (4 waves/SIMD is forced by block size).
//  step loop (2 barriers/step), only true recurrences:
//    P1: z-partials (rc[64], 2-way k-split over 1024 threads -> Pz[2][512])
//        + prior-mean partials (threads 768.., wf[16], 4-way split -> Pf)
//    P2: t<128: gate math + h update; t in[128,192): prior-mean combine
//  chunk phase (parallel, per 16 steps): obs@K az-GEMM (pre-staged),
//    Wr heads + prior-scale (from m_{t-1} archive) + KL, weights from L2.
// ---------------------------------------------------------------------------
__global__ __launch_bounds__(1024, 1) void kFused(
    const float* __restrict__ obs, const float* __restrict__ K,
    const float* __restrict__ bl,  const float* __restrict__ Rw,
    const float* __restrict__ Wfm, const float* __restrict__ bfm,
    const float* __restrict__ Wfs, const float* __restrict__ bfs,
    const float* __restrict__ im,
    const float* __restrict__ Wrm, const float* __restrict__ brm,
    const float* __restrict__ Wrs, const float* __restrict__ brs,
    float* __restrict__ qpm, double* __restrict__ acc_out)
{
    __shared__ float sobs[CH * 128];    // obs chunk, natural [s][k]      8.0 KB
    __shared__ float azs[CH * 512];     // obs@K for chunk [s][col]      32.0 KB
    __shared__ float hch[CH * 132];     // h archive [s][k] (pad 4)       8.4 KB
    __shared__ float qch[CH * 132];     // head out: qm | sp              8.4 KB
    __shared__ float prmch[CH * 68];    // prior mean archive             4.3 KB
    __shared__ float sqch[CH * 68];     // prior scale                    4.3 KB
    __shared__ float Pz[2 * 516];       // z partials (2-way k-split)     4.1 KB
    __shared__ float Pf[4 * 68];        // prior-mean partials            1.1 KB
    __shared__ float h_lds[128];
    __shared__ float m_lds[64];
    __shared__ float m0ch[64];          // m at chunk start
    __shared__ float wred[16];

    const int t = threadIdx.x;
    const int b = blockIdx.x;

    // ---- z-matvec ownership: col zc, k-half kh ----
    const int zc = t & 511;
    const int kh = t >> 9;  // 0 or 1
    float rc[64];
#pragma unroll
    for (int kk = 0; kk < 64; ++kk) rc[kk] = Rw[(kh * 64 + kk) * 512 + zc];

    // ---- prior-mean partial ownership (threads 768..1023) ----
    const int pc = t & 63;
    const int pq = (t >> 6) & 3;
    float wf[16];
    if (t >= 768) {
#pragma unroll
        for (int kk = 0; kk < 16; ++kk) wf[kk] = Wfm[(pq * 16 + kk) * 64 + pc];
    }

    // ---- role constants ----
    float bl0 = 0.f, bl1 = 0.f, bl2 = 0.f, bl3 = 0.f, cst = 0.f, bfmr = 0.f;
    if (t < 128) { bl0 = bl[t]; bl1 = bl[t + 128]; bl2 = bl[t + 256]; bl3 = bl[t + 384]; }
    else if (t < 192) bfmr = bfm[t - 128];

    // ---- head job constants: cols hc for steps hs2 and hs2+8 ----
    const int hc  = t & 127;
    const int hs2 = t >> 7;  // 0..7
    const float* Wcol = (hc < 64) ? (Wrm + hc) : (Wrs + (hc - 64));
    const float hbias = (hc < 64) ? brm[hc] : brs[hc - 64];
    // ---- prior-scale / KL job constants: (step ss, col pc) ----
    const int ss = t >> 6;   // 0..15
    const float bfsr = bfs[pc];

    float acckl = 0.f;
    if (t < 128) h_lds[t] = 0.f;
    if (t < 64)  m_lds[t] = im[b * 64 + t];
    __syncthreads();

    const float* obsb = obs + (size_t)b * TT * OO;
    float* qrow = qpm + (size_t)b * TT * SS;

    for (int t0 = 0; t0 < TT; t0 += CH) {
        // ---- stage obs chunk + m at chunk start ----
        if (t < 512) ((float4*)sobs)[t] = ((const float4*)(obsb + (size_t)t0 * OO))[t];
        if (t < 64) m0ch[t] = m_lds[t];
        __syncthreads();  // A: sobs/m0ch ready

        // ---- az chunk GEMM: thread (zc, kh) -> steps kh*8..kh*8+7, col zc ----
        {
            float az[8];
#pragma unroll
            for (int j = 0; j < 8; ++j) az[j] = 0.f;
            const float* srow = sobs + (kh * 8) * 128;
            for (int kb = 0; kb < 32; ++kb) {
                const float k0 = K[(4 * kb + 0) * 512 + zc];
                const float k1 = K[(4 * kb + 1) * 512 + zc];
                const float k2 = K[(4 * kb + 2) * 512 + zc];
                const float k3 = K[(4 * kb + 3) * 512 + zc];
#pragma unroll
                for (int j = 0; j < 8; ++j) {
                    const float4 o = *(const float4*)&srow[j * 128 + 4 * kb];
                    az[j] += o.x * k0 + o.y * k1 + o.z * k2 + o.w * k3;
                }
            }
#pragma unroll
            for (int j = 0; j < 8; ++j) azs[(kh * 8 + j) * 512 + zc] = az[j];
            // azs reads are protected by B1 of step 0
        }

        // ---- 16 sequential steps, 2 barriers each ----
#pragma unroll 1
        for (int si = 0; si < CH; ++si) {
            // P1: z partial for (zc, kh)
            {
                const float4* h4 = (const float4*)&h_lds[kh * 64];
                float a0 = 0.f, a1 = 0.f, a2 = 0.f, a3 = 0.f;
#pragma unroll
                for (int kb = 0; kb < 16; ++kb) {
                    const float4 v = h4[kb];
                    a0 += v.x * rc[4 * kb + 0];
                    a1 += v.y * rc[4 * kb + 1];
                    a2 += v.z * rc[4 * kb + 2];
                    a3 += v.w * rc[4 * kb + 3];
                }
                Pz[kh * 516 + zc] = (a0 + a1) + (a2 + a3);
            }
            // P1b: prior-mean partial (threads 768..1023)
            if (t >= 768) {
                const float4* m4 = (const float4*)&m_lds[pq * 16];
                float p0 = 0.f, p1 = 0.f, p2 = 0.f, p3 = 0.f;
#pragma unroll
                for (int kb = 0; kb < 4; ++kb) {
                    const float4 v = m4[kb];
                    p0 += v.x * wf[4 * kb + 0];
                    p1 += v.y * wf[4 * kb + 1];
                    p2 += v.z * wf[4 * kb + 2];
                    p3 += v.w * wf[4 * kb + 3];
                }
                Pf[pq * 68 + pc] = (p0 + p1) + (p2 + p3);
            }
            __syncthreads();  // B1

            // P2: roles
            if (t < 128) {
                const float* az_ = &azs[si * 512];
                const float zi = Pz[t]       + Pz[516 + t]       + az_[t]       + bl0;
                const float zf = Pz[t + 128] + Pz[516 + t + 128] + az_[t + 128] + bl1;
                const float zg = Pz[t + 256] + Pz[516 + t + 256] + az_[t + 256] + bl2;
                const float zo = Pz[t + 384] + Pz[516 + t + 384] + az_[t + 384] + bl3;
                cst = sigmoidf(zf) * cst + sigmoidf(zi) * tanhf(zg);
                const float h = sigmoidf(zo) * tanhf(cst);
                h_lds[t] = h;
                hch[si * 132 + t] = h;
            } else if (t < 192) {
                const int c = t - 128;
                const float pm = Pf[c] + Pf[68 + c] + Pf[136 + c] + Pf[204 + c] + bfmr;
                m_lds[c] = pm;
                prmch[si * 68 + c] = pm;
            }
            __syncthreads();  // B2
        }

        // ---- chunk phase: heads (2 jobs) + prior-scale (1 job) per thread ----
        {
            float qA0 = 0.f, qA1 = 0.f, qA2 = 0.f, qA3 = 0.f;
            float qB0 = 0.f, qB1 = 0.f, qB2 = 0.f, qB3 = 0.f;
            const float* hA = &hch[hs2 * 132];
            const float* hB = &hch[(hs2 + 8) * 132];
#pragma unroll 4
            for (int kb = 0; kb < 32; ++kb) {
                const float w0 = Wcol[(4 * kb + 0) * 64];
                const float w1 = Wcol[(4 * kb + 1) * 64];
                const float w2 = Wcol[(4 * kb + 2) * 64];
                const float w3 = Wcol[(4 * kb + 3) * 64];
                const float4 a = *(const float4*)&hA[4 * kb];
                const float4 bv = *(const float4*)&hB[4 * kb];
                qA0 += a.x * w0;  qA1 += a.y * w1;  qA2 += a.z * w2;  qA3 += a.w * w3;
                qB0 += bv.x * w0; qB1 += bv.y * w1; qB2 += bv.z * w2; qB3 += bv.w * w3;
            }
            const float qA = (qA0 + qA1) + (qA2 + qA3) + hbias;
            const float qB = (qB0 + qB1) + (qB2 + qB3) + hbias;
            if (hc < 64) {
                qch[hs2 * 132 + hc] = qA;
                qch[(hs2 + 8) * 132 + hc] = qB;
                qrow[(size_t)(t0 + hs2) * SS + hc] = qA;
                qrow[(size_t)(t0 + hs2 + 8) * SS + hc] = qB;
            } else {
                qch[hs2 * 132 + hc] = softplusf(qA);
                qch[(hs2 + 8) * 132 + hc] = softplusf(qB);
            }

            // prior scale for (ss, pc): uses m_{ts-1}
            const float* m_in = (ss == 0) ? m0ch : &prmch[(ss - 1) * 68];
            float s0 = 0.f, s1 = 0.f, s2 = 0.f, s3 = 0.f;
#pragma unroll 4
            for (int kb = 0; kb < 16; ++kb) {
                const float w0 = Wfs[(4 * kb + 0) * 64 + pc];
                const float w1 = Wfs[(4 * kb + 1) * 64 + pc];
                const float w2 = Wfs[(4 * kb + 2) * 64 + pc];
                const float w3 = Wfs[(4 * kb + 3) * 64 + pc];
                const float4 mv = *(const float4*)&m_in[4 * kb];
                s0 += mv.x * w0; s1 += mv.y * w1; s2 += mv.z * w2; s3 += mv.w * w3;
            }
            sqch[ss * 68 + pc] = softplusf((s0 + s1) + (s2 + s3) + bfsr);
        }
        __syncthreads();  // C: qch/sqch ready

        // ---- KL for (ss, pc) ----
        {
            const float qm = qch[ss * 132 + pc];
            const float sp = qch[ss * 132 + 64 + pc];
            const float pm = prmch[ss * 68 + pc];
            const float sq = sqch[ss * 68 + pc];
            const float d = qm - pm;
            acckl += logf(sq) - logf(sp) + (sp * sp + d * d) / (2.f * sq * sq) - 0.5f;
        }
        // no barrier needed: next writes to prmch/qch/azs are all behind B1/B2
    }

    // ---- reduce KL: wave shuffle -> 16 partials -> atomic ----
    for (int off = 32; off > 0; off >>= 1) acckl += __shfl_down(acckl, off, 64);
    if ((t & 63) == 0) wred[t >> 6] = acckl;
    __syncthreads();
    if (t == 0) {
        float s = 0.f;
#pragma unroll
        for (int w = 0; w < 16; ++w) s += wred[w];
        atomicAdd(acc_out, (double)s * (1.0 / ((double)BB * (double)TT)));
    }
}

// ---------------- Kernel C2: generator heads + reconstruction -----------------
// 128 threads: thread t owns Wg_m[:,t] and Wg_s[:,t] (64+64 regs). 128 pos/block.
__global__ __launch_bounds__(128) void kC2(const float* __restrict__ obs,
                                           const float* __restrict__ qpm,
                                           const float* __restrict__ Wgm,
                                           const float* __restrict__ bgm,
                                           const float* __restrict__ Wgs,
                                           const float* __restrict__ bgs,
                                           double* __restrict__ acc_out) {
    __shared__ float red[128];
    const int t = threadIdx.x;
    float wgm[64], wgs[64];
#pragma unroll
    for (int k = 0; k < 64; ++k) {
        wgm[k] = Wgm[k * 128 + t];
        wgs[k] = Wgs[k * 128 + t];
    }
    const float bm = bgm[t];
    const float bs = bgs[t];

    float accr = 0.f;
    const size_t p0 = (size_t)blockIdx.x * 128;
    for (int i = 0; i < 128; ++i) {
        const size_t p = p0 + i;
        const float4* m4 = (const float4*)(qpm + p * 64);
        float m0 = 0.f, m1 = 0.f, m2 = 0.f, m3 = 0.f;
        float s0 = 0.f, s1 = 0.f, s2 = 0.f, s3 = 0.f;
#pragma unroll
        for (int kb = 0; kb < 16; ++kb) {
            const float4 v = m4[kb];
            m0 += v.x * wgm[kb * 4 + 0];
            m1 += v.y * wgm[kb * 4 + 1];
            m2 += v.z * wgm[kb * 4 + 2];
            m3 += v.w * wgm[kb * 4 + 3];
            s0 += v.x * wgs[kb * 4 + 0];
            s1 += v.y * wgs[kb * 4 + 1];
            s2 += v.z * wgs[kb * 4 + 2];
            s3 += v.w * wgs[kb * 4 + 3];
        }
        const float om = bm + ((m0 + m1) + (m2 + m3));
        const float os = softplusf(bs + ((s0 + s1) + (s2 + s3)));
        const float x = obs[p * 128 + t];
        const float d = (x - om) / os;
        accr += 0.5f * d * d + logf(os) + 0.5f * LOG2PI_F;
    }
    red[t] = accr;
    __syncthreads();
    for (int s = 64; s > 0; s >>= 1) {
        if (t < s) red[t] += red[t + s];
        __syncthreads();
    }
    if (t == 0) atomicAdd(acc_out, (double)red[0] * (1.0 / (double)BB));
}

extern "C" void kernel_launch(void* const* d_in, const int* in_sizes, int n_in,
                              void* d_out, int out_size, void* d_ws, size_t ws_size,
                              hipStream_t stream) {
    (void)in_sizes; (void)n_in; (void)out_size; (void)ws_size;

    const float* obs = (const float*)d_in[0];
    const float* im  = (const float*)d_in[1];
    // d_in[2] initial_scale: unused by the reference forward
    const float* Wfm = (const float*)d_in[3];
    const float* bfm = (const float*)d_in[4];
    const float* Wfs = (const float*)d_in[5];
    const float* bfs = (const float*)d_in[6];
    const float* Wgm = (const float*)d_in[7];
    const float* bgm = (const float*)d_in[8];
    const float* Wgs = (const float*)d_in[9];
    const float* bgs = (const float*)d_in[10];
    const float* K   = (const float*)d_in[11];
    const float* Rw  = (const float*)d_in[12];
    const float* bl  = (const float*)d_in[13];
    const float* Wrm = (const float*)d_in[14];
    const float* brm = (const float*)d_in[15];
    const float* Wrs = (const float*)d_in[16];
    const float* brs = (const float*)d_in[17];

    double* acc = (double*)((char*)d_ws + ACC_OFF);
    float* qpm  = (float*)((char*)d_ws + QPM_OFF);

    zero_acc_kernel<<<1, 1, 0, stream>>>(acc);
    kFused<<<BB, 1024, 0, stream>>>(obs, K, bl, Rw, Wfm, bfm, Wfs, bfs, im,
                                    Wrm, brm, Wrs, brs, qpm, acc);
    kC2<<<(BB * TT) / 128, 128, 0, stream>>>(obs, qpm, Wgm, bgm, Wgs, bgs, acc);
    finalize_kernel<<<1, 1, 0, stream>>>(acc, (float*)d_out);
}

// Round 6
// 1815.029 us; speedup vs baseline: 1.8245x; 1.0143x over previous
//
#include <hip/hip_runtime.h>
#include <math.h>

// Problem constants (match reference)
#define BB 256
#define TT 512
#define SS 64
#define OO 128
#define HH 128
#define FH 512  // 4*H
#define CH 16   // time-chunk

#define LOG2PI_F 1.8378770664093453f

// ws layout (bytes): [acc: 8B][pad][qpm: B*T*S*4 = 32MB]
#define ACC_OFF 0
#define QPM_OFF 256

__device__ __forceinline__ float softplusf(float x) {
    // matches jax.nn.softplus: max(x,0) + log1p(exp(-|x|))
    return fmaxf(x, 0.f) + log1pf(expf(-fabsf(x)));
}
__device__ __forceinline__ float sigmoidf(float x) {
    return 1.f / (1.f + expf(-x));
}

__global__ void zero_acc_kernel(double* acc) { acc[0] = 0.0; }
__global__ void finalize_kernel(const double* acc, float* out) { out[0] = (float)acc[0]; }

// ---------------------------------------------------------------------------
// Fused kernel: one block per batch (256 blocks x 1024 threads = 16 waves).
// LDS=73KB -> exactly 1 block/CU = 16 waves = 4 waves/SIMD. Therefore pin the
// register allocator to 4 waves/EU (128-VGPR budget): R5 showed it targeting
// 64 VGPR (8 waves/EU it can never reach) and spilling ~46 regs/thread
// (28MB scratch writes, VALUBusy 54%).
//  step loop (2 barriers/step), only true recurrences:
//    P1: z-partials (rc[64], 2-way k-split over 1024 threads -> Pz[2][512])
//        + prior-mean partials (threads 768.., wf[16], 4-way split -> Pf)
//    P2: t<128: gate math + h update; t in[128,192): prior-mean combine
//  chunk phase (parallel, per 16 steps): obs@K az-GEMM (pre-staged),
//    Wr heads + prior-scale (from m_{t-1} archive) + KL, weights from L2.
// ---------------------------------------------------------------------------
__global__ __launch_bounds__(1024) __attribute__((amdgpu_waves_per_eu(4, 4)))
void kFused(
    const float* __restrict__ obs, const float* __restrict__ K,
    const float* __restrict__ bl,  const float* __restrict__ Rw,
    const float* __restrict__ Wfm, const float* __restrict__ bfm,
    const float* __restrict__ Wfs, const float* __restrict__ bfs,
    const float* __restrict__ im,
    const float* __restrict__ Wrm, const float* __restrict__ brm,
    const float* __restrict__ Wrs, const float* __restrict__ brs,
    float* __restrict__ qpm, double* __restrict__ acc_out)
{
    __shared__ float sobs[CH * 128];    // obs chunk, natural [s][k]      8.0 KB
    __shared__ float azs[CH * 512];     // obs@K for chunk [s][col]      32.0 KB
    __shared__ float hch[CH * 132];     // h archive [s][k] (pad 4)       8.4 KB
    __shared__ float qch[CH * 132];     // head out: qm | sp              8.4 KB
    __shared__ float prmch[CH * 68];    // prior mean archive             4.3 KB
    __shared__ float sqch[CH * 68];     // prior scale                    4.3 KB
    __shared__ float Pz[2 * 516];       // z partials (2-way k-split)     4.1 KB
    __shared__ float Pf[4 * 68];        // prior-mean partials            1.1 KB
    __shared__ float h_lds[128];
    __shared__ float m_lds[64];
    __shared__ float m0ch[64];          // m at chunk start
    __shared__ float wred[16];

    const int t = threadIdx.x;
    const int b = blockIdx.x;

    // ---- z-matvec ownership: col zc, k-half kh ----
    const int zc = t & 511;
    const int kh = t >> 9;  // 0 or 1
    float rc[64];
#pragma unroll
    for (int kk = 0; kk < 64; ++kk) rc[kk] = Rw[(kh * 64 + kk) * 512 + zc];

    // ---- prior-mean partial ownership (threads 768..1023) ----
    const int pc = t & 63;
    const int pq = (t >> 6) & 3;
    float wf[16];
    if (t >= 768) {
#pragma unroll
        for (int kk = 0; kk < 16; ++kk) wf[kk] = Wfm[(pq * 16 + kk) * 64 + pc];
    }

    // ---- role constants ----
    float bl0 = 0.f, bl1 = 0.f, bl2 = 0.f, bl3 = 0.f, cst = 0.f, bfmr = 0.f;
    if (t < 128) { bl0 = bl[t]; bl1 = bl[t + 128]; bl2 = bl[t + 256]; bl3 = bl[t + 384]; }
    else if (t < 192) bfmr = bfm[t - 128];

    // ---- head job constants: cols hc for steps hs2 and hs2+8 ----
    const int hc  = t & 127;
    const int hs2 = t >> 7;  // 0..7
    const float* Wcol = (hc < 64) ? (Wrm + hc) : (Wrs + (hc - 64));
    const float hbias = (hc < 64) ? brm[hc] : brs[hc - 64];
    // ---- prior-scale / KL job constants: (step ss, col pc) ----
    const int ss = t >> 6;   // 0..15
    const float bfsr = bfs[pc];

    float acckl = 0.f;
    if (t < 128) h_lds[t] = 0.f;
    if (t < 64)  m_lds[t] = im[b * 64 + t];
    __syncthreads();

    const float* obsb = obs + (size_t)b * TT * OO;
    float* qrow = qpm + (size_t)b * TT * SS;

    for (int t0 = 0; t0 < TT; t0 += CH) {
        // ---- stage obs chunk + m at chunk start ----
        if (t < 512) ((float4*)sobs)[t] = ((const float4*)(obsb + (size_t)t0 * OO))[t];
        if (t < 64) m0ch[t] = m_lds[t];
        __syncthreads();  // A: sobs/m0ch ready

        // ---- az chunk GEMM: thread (zc, kh) -> steps kh*8..kh*8+7, col zc ----
        {
            float az[8];
#pragma unroll
            for (int j = 0; j < 8; ++j) az[j] = 0.f;
            const float* srow = sobs + (kh * 8) * 128;
            for (int kb = 0; kb < 32; ++kb) {
                const float k0 = K[(4 * kb + 0) * 512 + zc];
                const float k1 = K[(4 * kb + 1) * 512 + zc];
                const float k2 = K[(4 * kb + 2) * 512 + zc];
                const float k3 = K[(4 * kb + 3) * 512 + zc];
#pragma unroll
                for (int j = 0; j < 8; ++j) {
                    const float4 o = *(const float4*)&srow[j * 128 + 4 * kb];
                    az[j] += o.x * k0 + o.y * k1 + o.z * k2 + o.w * k3;
                }
            }
#pragma unroll
            for (int j = 0; j < 8; ++j) azs[(kh * 8 + j) * 512 + zc] = az[j];
            // azs reads are protected by B1 of step 0
        }

        // ---- 16 sequential steps, 2 barriers each ----
#pragma unroll 1
        for (int si = 0; si < CH; ++si) {
            // P1: z partial for (zc, kh)
            {
                const float4* h4 = (const float4*)&h_lds[kh * 64];
                float a0 = 0.f, a1 = 0.f, a2 = 0.f, a3 = 0.f;
#pragma unroll
                for (int kb = 0; kb < 16; ++kb) {
                    const float4 v = h4[kb];
                    a0 += v.x * rc[4 * kb + 0];
                    a1 += v.y * rc[4 * kb + 1];
                    a2 += v.z * rc[4 * kb + 2];
                    a3 += v.w * rc[4 * kb + 3];
                }
                Pz[kh * 516 + zc] = (a0 + a1) + (a2 + a3);
            }
            // P1b: prior-mean partial (threads 768..1023)
            if (t >= 768) {
                const float4* m4 = (const float4*)&m_lds[pq * 16];
                float p0 = 0.f, p1 = 0.f, p2 = 0.f, p3 = 0.f;
#pragma unroll
                for (int kb = 0; kb < 4; ++kb) {
                    const float4 v = m4[kb];
                    p0 += v.x * wf[4 * kb + 0];
                    p1 += v.y * wf[4 * kb + 1];
                    p2 += v.z * wf[4 * kb + 2];
                    p3 += v.w * wf[4 * kb + 3];
                }
                Pf[pq * 68 + pc] = (p0 + p1) + (p2 + p3);
            }
            __syncthreads();  // B1

            // P2: roles
            if (t < 128) {
                const float* az_ = &azs[si * 512];
                const float zi = Pz[t]       + Pz[516 + t]       + az_[t]       + bl0;
                const float zf = Pz[t + 128] + Pz[516 + t + 128] + az_[t + 128] + bl1;
                const float zg = Pz[t + 256] + Pz[516 + t + 256] + az_[t + 256] + bl2;
                const float zo = Pz[t + 384] + Pz[516 + t + 384] + az_[t + 384] + bl3;
                cst = sigmoidf(zf) * cst + sigmoidf(zi) * tanhf(zg);
                const float h = sigmoidf(zo) * tanhf(cst);
                h_lds[t] = h;
                hch[si * 132 + t] = h;
            } else if (t < 192) {
                const int c = t - 128;
                const float pm = Pf[c] + Pf[68 + c] + Pf[136 + c] + Pf[204 + c] + bfmr;
                m_lds[c] = pm;
                prmch[si * 68 + c] = pm;
            }
            __syncthreads();  // B2
        }

        // ---- chunk phase: heads (2 jobs) + prior-scale (1 job) per thread ----
        {
            float qA0 = 0.f, qA1 = 0.f, qA2 = 0.f, qA3 = 0.f;
            float qB0 = 0.f, qB1 = 0.f, qB2 = 0.f, qB3 = 0.f;
            const float* hA = &hch[hs2 * 132];
            const float* hB = &hch[(hs2 + 8) * 132];
#pragma unroll 4
            for (int kb = 0; kb < 32; ++kb) {
                const float w0 = Wcol[(4 * kb + 0) * 64];
                const float w1 = Wcol[(4 * kb + 1) * 64];
                const float w2 = Wcol[(4 * kb + 2) * 64];
                const float w3 = Wcol[(4 * kb + 3) * 64];
                const float4 a = *(const float4*)&hA[4 * kb];
                const float4 bv = *(const float4*)&hB[4 * kb];
                qA0 += a.x * w0;  qA1 += a.y * w1;  qA2 += a.z * w2;  qA3 += a.w * w3;
                qB0 += bv.x * w0; qB1 += bv.y * w1; qB2 += bv.z * w2; qB3 += bv.w * w3;
            }
            const float qA = (qA0 + qA1) + (qA2 + qA3) + hbias;
            const float qB = (qB0 + qB1) + (qB2 + qB3) + hbias;
            if (hc < 64) {
                qch[hs2 * 132 + hc] = qA;
                qch[(hs2 + 8) * 132 + hc] = qB;
                qrow[(size_t)(t0 + hs2) * SS + hc] = qA;
                qrow[(size_t)(t0 + hs2 + 8) * SS + hc] = qB;
            } else {
                qch[hs2 * 132 + hc] = softplusf(qA);
                qch[(hs2 + 8) * 132 + hc] = softplusf(qB);
            }

            // prior scale for (ss, pc): uses m_{ts-1}
            const float* m_in = (ss == 0) ? m0ch : &prmch[(ss - 1) * 68];
            float s0 = 0.f, s1 = 0.f, s2 = 0.f, s3 = 0.f;
#pragma unroll 4
            for (int kb = 0; kb < 16; ++kb) {
                const float w0 = Wfs[(4 * kb + 0) * 64 + pc];
                const float w1 = Wfs[(4 * kb + 1) * 64 + pc];
                const float w2 = Wfs[(4 * kb + 2) * 64 + pc];
                const float w3 = Wfs[(4 * kb + 3) * 64 + pc];
                const float4 mv = *(const float4*)&m_in[4 * kb];
                s0 += mv.x * w0; s1 += mv.y * w1; s2 += mv.z * w2; s3 += mv.w * w3;
            }
            sqch[ss * 68 + pc] = softplusf((s0 + s1) + (s2 + s3) + bfsr);
        }
        __syncthreads();  // C: qch/sqch ready

        // ---- KL for (ss, pc) ----
        {
            const float qm = qch[ss * 132 + pc];
            const float sp = qch[ss * 132 + 64 + pc];
            const float pm = prmch[ss * 68 + pc];
            const float sq = sqch[ss * 68 + pc];
            const float d = qm - pm;
            acckl += logf(sq) - logf(sp) + (sp * sp + d * d) / (2.f * sq * sq) - 0.5f;
        }
        // no barrier needed: next writes to prmch/qch/azs are all behind B1/B2
    }

    // ---- reduce KL: wave shuffle -> 16 partials -> atomic ----
    for (int off = 32; off > 0; off >>= 1) acckl += __shfl_down(acckl, off, 64);
    if ((t & 63) == 0) wred[t >> 6] = acckl;
    __syncthreads();
    if (t == 0) {
        float s = 0.f;
#pragma unroll
        for (int w = 0; w < 16; ++w) s += wred[w];
        atomicAdd(acc_out, (double)s * (1.0 / ((double)BB * (double)TT)));
    }
}

// ---------------- Kernel C2: generator heads + reconstruction -----------------
// 128 threads: thread t owns Wg_m[:,t] and Wg_s[:,t] (64+64 regs). 128 pos/block.
__global__ __launch_bounds__(128) void kC2(const float* __restrict__ obs,
                                           const float* __restrict__ qpm,
                                           const float* __restrict__ Wgm,
                                           const float* __restrict__ bgm,
                                           const float* __restrict__ Wgs,
                                           const float* __restrict__ bgs,
                                           double* __restrict__ acc_out) {
    __shared__ float red[128];
    const int t = threadIdx.x;
    float wgm[64], wgs[64];
#pragma unroll
    for (int k = 0; k < 64; ++k) {
        wgm[k] = Wgm[k * 128 + t];
        wgs[k] = Wgs[k * 128 + t];
    }
    const float bm = bgm[t];
    const float bs = bgs[t];

    float accr = 0.f;
    const size_t p0 = (size_t)blockIdx.x * 128;
    for (int i = 0; i < 128; ++i) {
        const size_t p = p0 + i;
        const float4* m4 = (const float4*)(qpm + p * 64);
        float m0 = 0.f, m1 = 0.f, m2 = 0.f, m3 = 0.f;
        float s0 = 0.f, s1 = 0.f, s2 = 0.f, s3 = 0.f;
#pragma unroll
        for (int kb = 0; kb < 16; ++kb) {
            const float4 v = m4[kb];
            m0 += v.x * wgm[kb * 4 + 0];
            m1 += v.y * wgm[kb * 4 + 1];
            m2 += v.z * wgm[kb * 4 + 2];
            m3 += v.w * wgm[kb * 4 + 3];
            s0 += v.x * wgs[kb * 4 + 0];
            s1 += v.y * wgs[kb * 4 + 1];
            s2 += v.z * wgs[kb * 4 + 2];
            s3 += v.w * wgs[kb * 4 + 3];
        }
        const float om = bm + ((m0 + m1) + (m2 + m3));
        const float os = softplusf(bs + ((s0 + s1) + (s2 + s3)));
        const float x = obs[p * 128 + t];
        const float d = (x - om) / os;
        accr += 0.5f * d * d + logf(os) + 0.5f * LOG2PI_F;
    }
    red[t] = accr;
    __syncthreads();
    for (int s = 64; s > 0; s >>= 1) {
        if (t < s) red[t] += red[t + s];
        __syncthreads();
    }
    if (t == 0) atomicAdd(acc_out, (double)red[0] * (1.0 / (double)BB));
}

extern "C" void kernel_launch(void* const* d_in, const int* in_sizes, int n_in,
                              void* d_out, int out_size, void* d_ws, size_t ws_size,
                              hipStream_t stream) {
    (void)in_sizes; (void)n_in; (void)out_size; (void)ws_size;

    const float* obs = (const float*)d_in[0];
    const float* im  = (const float*)d_in[1];
    // d_in[2] initial_scale: unused by the reference forward
    const float* Wfm = (const float*)d_in[3];
    const float* bfm = (const float*)d_in[4];
    const float* Wfs = (const float*)d_in[5];
    const float* bfs = (const float*)d_in[6];
    const float* Wgm = (const float*)d_in[7];
    const float* bgm = (const float*)d_in[8];
    const float* Wgs = (const float*)d_in[9];
    const float* bgs = (const float*)d_in[10];
    const float* K   = (const float*)d_in[11];
    const float* Rw  = (const float*)d_in[12];
    const float* bl  = (const float*)d_in[13];
    const float* Wrm = (const float*)d_in[14];
    const float* brm = (const float*)d_in[15];
    const float* Wrs = (const float*)d_in[16];
    const float* brs = (const float*)d_in[17];

    double* acc = (double*)((char*)d_ws + ACC_OFF);
    float* qpm  = (float*)((char*)d_ws + QPM_OFF);

    zero_acc_kernel<<<1, 1, 0, stream>>>(acc);
    kFused<<<BB, 1024, 0, stream>>>(obs, K, bl, Rw, Wfm, bfm, Wfs, bfs, im,
                                    Wrm, brm, Wrs, brs, qpm, acc);
    kC2<<<(BB * TT) / 128, 128, 0, stream>>>(obs, qpm, Wgm, bgm, Wgs, bgs, acc);
    finalize_kernel<<<1, 1, 0, stream>>>(acc, (float*)d_out);
}